// Round 1
// baseline (24.434 us; speedup 1.0000x reference)
//
#include <hip/hip_runtime.h>
#include <cmath>

#define IMG_W 512
#define NROWS 8192               // 16 batches * 512 rows
#define ROWS_PER_BLOCK 4
#define NBLOCKS (NROWS / ROWS_PER_BLOCK)   // 2048
#define TPB 128                  // 4 pixels per thread

struct WinW { float w[11]; };

__global__ __launch_bounds__(TPB) void ssim_rows(
    const float* __restrict__ img1, const float* __restrict__ img2,
    float* __restrict__ partial, WinW ww)
{
    __shared__ __align__(16) float r1[528];
    __shared__ __align__(16) float r2[528];
    const int tid = threadIdx.x;
    float acc = 0.f;

    const float C1 = 1e-4f;      // (0.01*1)^2
    const float C2 = 9e-4f;      // (0.03*1)^2

    for (int rr = 0; rr < ROWS_PER_BLOCK; ++rr) {
        const int row = blockIdx.x * ROWS_PER_BLOCK + rr;
        const long long base = (long long)row * IMG_W;

        __syncthreads();         // protect LDS reuse from previous iteration
        // stage row with halo of 5 each side; LDS index j <-> input col j-5
        for (int j = tid; j < 528; j += TPB) {
            const int c = j - 5;
            const bool in = (c >= 0) && (c < IMG_W);
            r1[j] = in ? img1[base + c] : 0.f;
            r2[j] = in ? img2[base + c] : 0.f;
        }
        __syncthreads();

        // each thread: pixels w = 4*tid .. 4*tid+3; needs LDS idx 4t .. 4t+13
        const int wb = 4 * tid;  // byte offset 16*tid -> aligned b128 reads
        float a[16], b[16];
        *(float4*)&a[0]  = *(const float4*)&r1[wb];
        *(float4*)&a[4]  = *(const float4*)&r1[wb + 4];
        *(float4*)&a[8]  = *(const float4*)&r1[wb + 8];
        *(float4*)&a[12] = *(const float4*)&r1[wb + 12];
        *(float4*)&b[0]  = *(const float4*)&r2[wb];
        *(float4*)&b[4]  = *(const float4*)&r2[wb + 4];
        *(float4*)&b[8]  = *(const float4*)&r2[wb + 8];
        *(float4*)&b[12] = *(const float4*)&r2[wb + 12];

        // precompute products once per window position (shared by 4 pixels)
        float aa[14], bb[14], ab[14];
        #pragma unroll
        for (int j = 0; j < 14; ++j) {
            aa[j] = a[j] * a[j];
            bb[j] = b[j] * b[j];
            ab[j] = a[j] * b[j];
        }

        #pragma unroll
        for (int p = 0; p < 4; ++p) {
            float mu1 = 0.f, mu2 = 0.f, s11 = 0.f, s22 = 0.f, s12 = 0.f;
            #pragma unroll
            for (int k = 0; k < 11; ++k) {
                const float wk = ww.w[k];
                mu1 = fmaf(wk, a[p + k],  mu1);
                mu2 = fmaf(wk, b[p + k],  mu2);
                s11 = fmaf(wk, aa[p + k], s11);
                s22 = fmaf(wk, bb[p + k], s22);
                s12 = fmaf(wk, ab[p + k], s12);
            }
            const float m12 = mu1 * mu2;
            const float m1s = mu1 * mu1;
            const float m2s = mu2 * mu2;
            const float num = (2.f * m12 + C1) * (2.f * (s12 - m12) + C2);
            const float den = (m1s + m2s + C1) * ((s11 - m1s) + (s22 - m2s) + C2);
            acc += num / den;
        }
    }

    // deterministic block reduction: wave shfl then LDS
    #pragma unroll
    for (int off = 32; off > 0; off >>= 1)
        acc += __shfl_down(acc, off, 64);
    __shared__ float wsum[TPB / 64];
    if ((tid & 63) == 0) wsum[tid >> 6] = acc;
    __syncthreads();
    if (tid == 0) partial[blockIdx.x] = wsum[0] + wsum[1];
}

__global__ __launch_bounds__(256) void ssim_final(
    const float* __restrict__ partial, float* __restrict__ out)
{
    const int tid = threadIdx.x;
    float s = 0.f;
    for (int i = tid; i < NBLOCKS; i += 256) s += partial[i];
    #pragma unroll
    for (int off = 32; off > 0; off >>= 1)
        s += __shfl_down(s, off, 64);
    __shared__ float ws[4];
    if ((tid & 63) == 0) ws[tid >> 6] = s;
    __syncthreads();
    if (tid == 0) {
        const float total = ws[0] + ws[1] + ws[2] + ws[3];
        // 10 fully-zero-padded H rows per image have ssim == 1 exactly:
        // 16 images * 10 rows * 512 cols = 81920 ones.
        // mean is over 16*522*512 = 4276224 elements (3 identical channels cancel).
        out[0] = 1.0f - (total + 81920.0f) / 4276224.0f;
    }
}

extern "C" void kernel_launch(void* const* d_in, const int* in_sizes, int n_in,
                              void* d_out, int out_size, void* d_ws, size_t ws_size,
                              hipStream_t stream) {
    const float* img1 = (const float*)d_in[0];
    const float* img2 = (const float*)d_in[1];
    float* out = (float*)d_out;
    float* partial = (float*)d_ws;   // 2048 floats = 8 KB scratch

    // Gaussian window, computed exactly like the reference:
    // exp in double -> cast f32, f32 sum, f32 divide.
    WinW ww;
    for (int i = 0; i < 11; ++i) {
        const double d = (double)(i - 5);
        ww.w[i] = (float)std::exp(-(d * d) / 4.5);
    }
    float s = 0.f;
    for (int i = 0; i < 11; ++i) s += ww.w[i];
    for (int i = 0; i < 11; ++i) ww.w[i] /= s;

    ssim_rows<<<NBLOCKS, TPB, 0, stream>>>(img1, img2, partial, ww);
    ssim_final<<<1, 256, 0, stream>>>(partial, out);
}

// Round 2
// 16.382 us; speedup vs baseline: 1.4915x; 1.4915x over previous
//
#include <hip/hip_runtime.h>
#include <cmath>

typedef float f32x2 __attribute__((ext_vector_type(2)));
typedef float f32x4 __attribute__((ext_vector_type(4)));

#define IMG_W 512
#define NROWS 8192                       // 16 batches * 512 rows
#define PAIRS_PER_BLOCK 2                // 2 row-pairs = 4 rows per block
#define NBLOCKS (NROWS / (2 * PAIRS_PER_BLOCK))   // 2048
#define TPB 128                          // 4 columns per thread

struct WinW { float w[11]; };

__global__ __launch_bounds__(TPB) void ssim_rows(
    const float* __restrict__ img1, const float* __restrict__ img2,
    float* __restrict__ partial, WinW ww)
{
    // interleaved row-pair lines: l[c] = {rowEven[c-5], rowOdd[c-5]}, halo zeros
    __shared__ __align__(16) f32x2 l1[528];
    __shared__ __align__(16) f32x2 l2[528];
    const int tid = threadIdx.x;

    const float C1 = 1e-4f;              // (0.01*1)^2
    const float C2 = 9e-4f;              // (0.03*1)^2

    f32x2 acc = {0.f, 0.f};

    for (int pp = 0; pp < PAIRS_PER_BLOCK; ++pp) {
        const int pairIdx = blockIdx.x * PAIRS_PER_BLOCK + pp;
        const long long r0 = (long long)pairIdx * 2 * IMG_W;   // even row base
        const int col = 4 * tid;

        // vectorized global loads: both rows, both images (coalesced 16B/lane)
        const f32x4 a0 = *(const f32x4*)&img1[r0 + col];
        const f32x4 a1 = *(const f32x4*)&img1[r0 + IMG_W + col];
        const f32x4 b0 = *(const f32x4*)&img2[r0 + col];
        const f32x4 b1 = *(const f32x4*)&img2[r0 + IMG_W + col];

        __syncthreads();                 // previous iteration's LDS reads done
        #pragma unroll
        for (int c = 0; c < 4; ++c) {
            l1[5 + col + c] = f32x2{a0[c], a1[c]};
            l2[5 + col + c] = f32x2{b0[c], b1[c]};
        }
        if (tid < 16) {                  // halo: idx 0..4 and 517..527 -> zero
            const int slot = (tid < 5) ? tid : (512 + tid);
            l1[slot] = f32x2{0.f, 0.f};
            l2[slot] = f32x2{0.f, 0.f};
        }
        __syncthreads();

        // window registers: pixels col..col+3 need lds idx col..col+13 (read 16)
        // 16B-aligned b128 reads: 2 interleaved columns per read
        f32x2 a[16], b[16];
        #pragma unroll
        for (int s = 0; s < 8; ++s) {
            *(f32x4*)&a[2 * s] = *(const f32x4*)&l1[col + 2 * s];
            *(f32x4*)&b[2 * s] = *(const f32x4*)&l2[col + 2 * s];
        }

        f32x2 mu1[4], mu2[4], s11[4], s22[4], s12[4];
        #pragma unroll
        for (int p = 0; p < 4; ++p) {
            mu1[p] = f32x2{0.f, 0.f}; mu2[p] = f32x2{0.f, 0.f};
            s11[p] = f32x2{0.f, 0.f}; s22[p] = f32x2{0.f, 0.f};
            s12[p] = f32x2{0.f, 0.f};
        }

        // per-column products computed once, consumed by covering pixels
        #pragma unroll
        for (int j = 0; j < 14; ++j) {
            const f32x2 aj = a[j], bj = b[j];
            const f32x2 aa = aj * aj, bb = bj * bj, ab = aj * bj;
            #pragma unroll
            for (int p = 0; p < 4; ++p) {
                const int k = j - p;
                if (k >= 0 && k < 11) {
                    const float wk = ww.w[k];
                    mu1[p] += wk * aj;
                    mu2[p] += wk * bj;
                    s11[p] += wk * aa;
                    s22[p] += wk * bb;
                    s12[p] += wk * ab;
                }
            }
        }

        #pragma unroll
        for (int p = 0; p < 4; ++p) {
            const f32x2 m12 = mu1[p] * mu2[p];
            const f32x2 m1s = mu1[p] * mu1[p];
            const f32x2 m2s = mu2[p] * mu2[p];
            const f32x2 num = (2.f * m12 + C1) * (2.f * (s12[p] - m12) + C2);
            const f32x2 den = (m1s + m2s + C1) * ((s11[p] - m1s) + (s22[p] - m2s) + C2);
            f32x2 r;
            r.x = __builtin_amdgcn_rcpf(den.x);   // ~1ulp, fine vs 1.9e-2 thr
            r.y = __builtin_amdgcn_rcpf(den.y);
            acc += num * r;
        }
    }

    float s = acc.x + acc.y;
    #pragma unroll
    for (int off = 32; off > 0; off >>= 1)
        s += __shfl_down(s, off, 64);
    __shared__ float wsum[TPB / 64];
    if ((tid & 63) == 0) wsum[tid >> 6] = s;
    __syncthreads();
    if (tid == 0) partial[blockIdx.x] = wsum[0] + wsum[1];
}

__global__ __launch_bounds__(256) void ssim_final(
    const float* __restrict__ partial, float* __restrict__ out)
{
    const int tid = threadIdx.x;
    float s = 0.f;
    for (int i = tid; i < NBLOCKS; i += 256) s += partial[i];
    #pragma unroll
    for (int off = 32; off > 0; off >>= 1)
        s += __shfl_down(s, off, 64);
    __shared__ float ws[4];
    if ((tid & 63) == 0) ws[tid >> 6] = s;
    __syncthreads();
    if (tid == 0) {
        const float total = ws[0] + ws[1] + ws[2] + ws[3];
        // 10 fully zero-padded H rows per image have ssim == 1 exactly:
        // 16 * 10 * 512 = 81920 ones; mean over 16*522*512 = 4276224.
        out[0] = 1.0f - (total + 81920.0f) / 4276224.0f;
    }
}

extern "C" void kernel_launch(void* const* d_in, const int* in_sizes, int n_in,
                              void* d_out, int out_size, void* d_ws, size_t ws_size,
                              hipStream_t stream) {
    const float* img1 = (const float*)d_in[0];
    const float* img2 = (const float*)d_in[1];
    float* out = (float*)d_out;
    float* partial = (float*)d_ws;       // 2048 floats = 8 KB scratch

    WinW ww;
    for (int i = 0; i < 11; ++i) {
        const double d = (double)(i - 5);
        ww.w[i] = (float)std::exp(-(d * d) / 4.5);
    }
    float s = 0.f;
    for (int i = 0; i < 11; ++i) s += ww.w[i];
    for (int i = 0; i < 11; ++i) ww.w[i] /= s;

    ssim_rows<<<NBLOCKS, TPB, 0, stream>>>(img1, img2, partial, ww);
    ssim_final<<<1, 256, 0, stream>>>(partial, out);
}